// Round 1
// baseline (267.774 us; speedup 1.0000x reference)
//
#include <hip/hip_runtime.h>

#define BDIM 8
#define NPTS 4096
#define KNEI 20
#define BN (BDIM*NPTS)        // 32768
#define NKCNT (NPTS*KNEI)     // 81920
#define EPSI 1e-5f
#define SLOPE 0.01f

typedef __attribute__((ext_vector_type(8))) short bf16x8;
typedef __attribute__((ext_vector_type(4))) float f32x4;

__device__ __forceinline__ unsigned short f2bf(float f) {
    unsigned u = __builtin_bit_cast(unsigned, f);
    u += 0x7FFFu + ((u >> 16) & 1u);
    return (unsigned short)(u >> 16);
}
__device__ __forceinline__ float bf2f(unsigned short h) {
    unsigned u = ((unsigned)h) << 16;
    return __builtin_bit_cast(float, u);
}

// ---------------- K0: u = x*W1a^T, v = x*(W1b-W1a)^T  (bf16 out) ----------------
__global__ __launch_bounds__(256) void k0_uv(const float* __restrict__ x,
        const float* __restrict__ W1, unsigned short* __restrict__ u,
        unsigned short* __restrict__ v) {
    __shared__ float wlds[64 * 129];     // W1 [64][128] padded stride 129
    __shared__ float xs[16 * 64];
    int tid = threadIdx.x;
    int m0 = blockIdx.x * 16;
    for (int i = tid; i < 8192; i += 256)
        wlds[(i >> 7) * 129 + (i & 127)] = W1[i];
    for (int i = tid; i < 1024; i += 256)
        xs[i] = x[m0 * 64 + i];
    __syncthreads();
    int o = tid & 63;
    int r0 = tid >> 6;   // 0..3
    float au[4] = {0.f, 0.f, 0.f, 0.f};
    float av[4] = {0.f, 0.f, 0.f, 0.f};
    for (int c = 0; c < 64; ++c) {
        float wa = wlds[o * 129 + c];
        float wb = wlds[o * 129 + 64 + c];
        float wd = wb - wa;
#pragma unroll
        for (int jj = 0; jj < 4; ++jj) {
            float xv = xs[(r0 + jj * 4) * 64 + c];
            au[jj] += xv * wa;
            av[jj] += xv * wd;
        }
    }
#pragma unroll
    for (int jj = 0; jj < 4; ++jj) {
        int m = m0 + r0 + jj * 4;
        u[m * 64 + o] = f2bf(au[jj]);
        v[m * 64 + o] = f2bf(av[jj]);
    }
}

// ---------------- K1: stats1 (sum, sumsq of h1 = u[ind]+v) per (b,c) ----------------
__global__ __launch_bounds__(256) void k1_stats1(const unsigned short* __restrict__ u,
        const unsigned short* __restrict__ v, const int* __restrict__ ind,
        float* __restrict__ s1) {   // s1: [0..511]=sum, [512..1023]=sumsq
    __shared__ int ind_s[320];
    __shared__ unsigned short vs[1024];
    __shared__ float part[256 * 4];
    int tid = threadIdx.x;
    int b = blockIdx.x >> 8;             // 256 blocks per batch
    int n0 = (blockIdx.x & 255) << 4;
    int base = b * NPTS + n0;
    for (int i = tid; i < 320; i += 256) ind_s[i] = ind[base * 20 + i];
    for (int i = tid; i < 1024; i += 256) vs[i] = v[base * 64 + i];
    __syncthreads();
    int c2 = (tid & 31) * 2;
    int rr = tid >> 5;
    float sA = 0.f, qA = 0.f, sB = 0.f, qB = 0.f;
    for (int j = 0; j < 40; ++j) {
        int r = rr + j * 8;
        int idx = ind_s[r];
        int p = r / 20;
        unsigned uu = *(const unsigned*)(u + idx * 64 + c2);
        float h0 = bf2f((unsigned short)(uu & 0xFFFF)) + bf2f(vs[p * 64 + c2]);
        float h1 = bf2f((unsigned short)(uu >> 16)) + bf2f(vs[p * 64 + c2 + 1]);
        sA += h0; qA += h0 * h0;
        sB += h1; qB += h1 * h1;
    }
    part[tid * 4 + 0] = sA; part[tid * 4 + 1] = qA;
    part[tid * 4 + 2] = sB; part[tid * 4 + 3] = qB;
    __syncthreads();
    if (tid < 128) {
        int c = tid & 63, st = tid >> 6;
        float acc = 0.f;
        for (int g = 0; g < 8; ++g)
            acc += part[(g * 32 + (c >> 1)) * 4 + (c & 1) * 2 + st];
        atomicAdd(&s1[st * 512 + b * 64 + c], acc);
    }
}

// ---- helper: load B-fragments (W row-major [64][64] fp32 -> bf16 frags) ----
__device__ __forceinline__ void load_bfrags(const float* __restrict__ W,
        int l15, int q, bf16x8 bw[4][2]) {
#pragma unroll
    for (int nt = 0; nt < 4; ++nt)
#pragma unroll
        for (int ks = 0; ks < 2; ++ks) {
            const float* wp = W + (nt * 16 + l15) * 64 + ks * 32 + q * 8;
            bf16x8 t;
#pragma unroll
            for (int j = 0; j < 8; ++j) t[j] = (short)f2bf(wp[j]);
            bw[nt][ks] = t;
        }
}

#define ASTR 72   // bufA row stride in bf16 elems (2-way bank aliasing only)

union ShrU {
    struct { int ind_s[320]; unsigned short vs[1024]; } st;
    float part[2048];   // [w:4][nt:4][q:4][l15:16][2]
};

// staging: build a1 = lrelu(norm1(u[ind]+v)) into bufA (bf16)
__device__ __forceinline__ void stage_a1(unsigned short* bufA, ShrU& shr,
        const unsigned short* __restrict__ u, const unsigned short* __restrict__ v,
        const int* __restrict__ ind, const float* __restrict__ s1,
        int b, int base, int tid) {
    for (int i = tid; i < 320; i += 256) shr.st.ind_s[i] = ind[base * 20 + i];
    for (int i = tid; i < 1024; i += 256) shr.st.vs[i] = v[base * 64 + i];
    int c2 = (tid & 31) * 2;
    const float inv = 1.0f / (float)NKCNT;
    float m1a = s1[b * 64 + c2] * inv;
    float m1b = s1[b * 64 + c2 + 1] * inv;
    float v1a = s1[512 + b * 64 + c2] * inv - m1a * m1a;
    float v1b = s1[512 + b * 64 + c2 + 1] * inv - m1b * m1b;
    float r1a = rsqrtf(v1a + EPSI), r1b = rsqrtf(v1b + EPSI);
    __syncthreads();
    int rr = tid >> 5;
    for (int j = 0; j < 40; ++j) {
        int r = rr + j * 8;
        int idx = shr.st.ind_s[r];
        int p = r / 20;
        unsigned uu = *(const unsigned*)(u + idx * 64 + c2);
        float h0 = bf2f((unsigned short)(uu & 0xFFFF)) + bf2f(shr.st.vs[p * 64 + c2]);
        float h1 = bf2f((unsigned short)(uu >> 16)) + bf2f(shr.st.vs[p * 64 + c2 + 1]);
        float a0 = (h0 - m1a) * r1a; a0 = a0 >= 0.f ? a0 : SLOPE * a0;
        float a1 = (h1 - m1b) * r1b; a1 = a1 >= 0.f ? a1 : SLOPE * a1;
        unsigned pk = (unsigned)f2bf(a0) | ((unsigned)f2bf(a1) << 16);
        *(unsigned*)&bufA[r * ASTR + c2] = pk;
    }
    __syncthreads();
}

// ---------------- K2: GEMM2 on a1, accumulate stats2 ----------------
__global__ __launch_bounds__(256) void k2_stats2(const unsigned short* __restrict__ u,
        const unsigned short* __restrict__ v, const int* __restrict__ ind,
        const float* __restrict__ W2, const float* __restrict__ s1,
        float* __restrict__ s2) {
    __shared__ unsigned short bufA[320 * ASTR];
    __shared__ ShrU shr;
    int tid = threadIdx.x;
    int b = blockIdx.x >> 8;
    int n0 = (blockIdx.x & 255) << 4;
    int base = b * NPTS + n0;
    stage_a1(bufA, shr, u, v, ind, s1, b, base, tid);

    int lane = tid & 63, w = tid >> 6;
    int l15 = lane & 15, q = lane >> 4;
    bf16x8 bw[4][2];
    load_bfrags(W2, l15, q, bw);
    f32x4 acc[5][4];
#pragma unroll
    for (int mt = 0; mt < 5; ++mt)
#pragma unroll
        for (int nt = 0; nt < 4; ++nt) acc[mt][nt] = (f32x4){0.f, 0.f, 0.f, 0.f};
#pragma unroll
    for (int mt = 0; mt < 5; ++mt) {
        int row = (w * 5 + mt) * 16 + l15;
        bf16x8 a0 = *(bf16x8*)&bufA[row * ASTR + q * 8];
        bf16x8 a1 = *(bf16x8*)&bufA[row * ASTR + 32 + q * 8];
#pragma unroll
        for (int nt = 0; nt < 4; ++nt) {
            acc[mt][nt] = __builtin_amdgcn_mfma_f32_16x16x32_bf16(a0, bw[nt][0], acc[mt][nt], 0, 0, 0);
            acc[mt][nt] = __builtin_amdgcn_mfma_f32_16x16x32_bf16(a1, bw[nt][1], acc[mt][nt], 0, 0, 0);
        }
    }
#pragma unroll
    for (int nt = 0; nt < 4; ++nt) {
        float ss = 0.f, qq = 0.f;
#pragma unroll
        for (int mt = 0; mt < 5; ++mt)
#pragma unroll
            for (int i = 0; i < 4; ++i) { float d = acc[mt][nt][i]; ss += d; qq += d * d; }
        int pi = (((w * 4 + nt) * 4 + q) * 16 + l15) * 2;
        shr.part[pi] = ss; shr.part[pi + 1] = qq;
    }
    __syncthreads();
    if (tid < 128) {
        int c = tid & 63, st = tid >> 6;
        int nt = c >> 4, cl = c & 15;
        float a = 0.f;
        for (int ww = 0; ww < 4; ++ww)
            for (int q2 = 0; q2 < 4; ++q2)
                a += shr.part[(((ww * 4 + nt) * 4 + q2) * 16 + cl) * 2 + st];
        atomicAdd(&s2[st * 512 + b * 64 + c], a);
    }
}

// ------- K3: GEMM2 -> norm2+lrelu -> GEMM3 -> stats3 + pre-norm max over k -------
__global__ __launch_bounds__(256) void k3_main(const unsigned short* __restrict__ u,
        const unsigned short* __restrict__ v, const int* __restrict__ ind,
        const float* __restrict__ W2, const float* __restrict__ W3,
        const float* __restrict__ s1, const float* __restrict__ s2,
        float* __restrict__ s3, float* __restrict__ out) {
    __shared__ unsigned short bufA[320 * ASTR];
    __shared__ ShrU shr;
    int tid = threadIdx.x;
    int b = blockIdx.x >> 8;
    int n0 = (blockIdx.x & 255) << 4;
    int base = b * NPTS + n0;
    stage_a1(bufA, shr, u, v, ind, s1, b, base, tid);

    int lane = tid & 63, w = tid >> 6;
    int l15 = lane & 15, q = lane >> 4;
    const float inv = 1.0f / (float)NKCNT;
    // norm2 params for this lane's 4 channels (c = nt*16 + l15)
    float m2[4], r2[4];
#pragma unroll
    for (int nt = 0; nt < 4; ++nt) {
        int c = nt * 16 + l15;
        float mm = s2[b * 64 + c] * inv;
        float vv = s2[512 + b * 64 + c] * inv - mm * mm;
        m2[nt] = mm; r2[nt] = rsqrtf(vv + EPSI);
    }
    bf16x8 bw[4][2];
    load_bfrags(W2, l15, q, bw);
    f32x4 acc[5][4];
#pragma unroll
    for (int mt = 0; mt < 5; ++mt)
#pragma unroll
        for (int nt = 0; nt < 4; ++nt) acc[mt][nt] = (f32x4){0.f, 0.f, 0.f, 0.f};
#pragma unroll
    for (int mt = 0; mt < 5; ++mt) {
        int row = (w * 5 + mt) * 16 + l15;
        bf16x8 a0 = *(bf16x8*)&bufA[row * ASTR + q * 8];
        bf16x8 a1 = *(bf16x8*)&bufA[row * ASTR + 32 + q * 8];
#pragma unroll
        for (int nt = 0; nt < 4; ++nt) {
            acc[mt][nt] = __builtin_amdgcn_mfma_f32_16x16x32_bf16(a0, bw[nt][0], acc[mt][nt], 0, 0, 0);
            acc[mt][nt] = __builtin_amdgcn_mfma_f32_16x16x32_bf16(a1, bw[nt][1], acc[mt][nt], 0, 0, 0);
        }
    }
    // a2 = lrelu(norm2(h2)) back into this wave's private slice of bufA
#pragma unroll
    for (int mt = 0; mt < 5; ++mt)
#pragma unroll
        for (int nt = 0; nt < 4; ++nt)
#pragma unroll
            for (int i = 0; i < 4; ++i) {
                float a = (acc[mt][nt][i] - m2[nt]) * r2[nt];
                a = a >= 0.f ? a : SLOPE * a;
                int row = (w * 5 + mt) * 16 + q * 4 + i;
                bufA[row * ASTR + nt * 16 + l15] = f2bf(a);
            }
    // GEMM3
    load_bfrags(W3, l15, q, bw);
#pragma unroll
    for (int mt = 0; mt < 5; ++mt)
#pragma unroll
        for (int nt = 0; nt < 4; ++nt) acc[mt][nt] = (f32x4){0.f, 0.f, 0.f, 0.f};
#pragma unroll
    for (int mt = 0; mt < 5; ++mt) {
        int row = (w * 5 + mt) * 16 + l15;
        bf16x8 a0 = *(bf16x8*)&bufA[row * ASTR + q * 8];
        bf16x8 a1 = *(bf16x8*)&bufA[row * ASTR + 32 + q * 8];
#pragma unroll
        for (int nt = 0; nt < 4; ++nt) {
            acc[mt][nt] = __builtin_amdgcn_mfma_f32_16x16x32_bf16(a0, bw[nt][0], acc[mt][nt], 0, 0, 0);
            acc[mt][nt] = __builtin_amdgcn_mfma_f32_16x16x32_bf16(a1, bw[nt][1], acc[mt][nt], 0, 0, 0);
        }
    }
    // stats3 partials + write pre-norm h3 to bufA (own slice)
#pragma unroll
    for (int nt = 0; nt < 4; ++nt) {
        float ss = 0.f, qq = 0.f;
#pragma unroll
        for (int mt = 0; mt < 5; ++mt)
#pragma unroll
            for (int i = 0; i < 4; ++i) {
                float d = acc[mt][nt][i];
                ss += d; qq += d * d;
                int row = (w * 5 + mt) * 16 + q * 4 + i;
                bufA[row * ASTR + nt * 16 + l15] = f2bf(d);
            }
        int pi = (((w * 4 + nt) * 4 + q) * 16 + l15) * 2;
        shr.part[pi] = ss; shr.part[pi + 1] = qq;
    }
    __syncthreads();
    if (tid < 128) {
        int c = tid & 63, st = tid >> 6;
        int nt = c >> 4, cl = c & 15;
        float a = 0.f;
        for (int ww = 0; ww < 4; ++ww)
            for (int q2 = 0; q2 < 4; ++q2)
                a += shr.part[(((ww * 4 + nt) * 4 + q2) * 16 + cl) * 2 + st];
        atomicAdd(&s3[st * 512 + b * 64 + c], a);
    }
    // pre-norm max over k=20 neighbors -> out  (norm3+lrelu commute with max)
    {
        int c = tid & 63;
        int p0 = tid >> 6;
#pragma unroll
        for (int ii = 0; ii < 4; ++ii) {
            int p = p0 * 4 + ii;
            float mx = -3.4e38f;
            for (int kk = 0; kk < 20; ++kk)
                mx = fmaxf(mx, bf2f(bufA[(p * 20 + kk) * ASTR + c]));
            out[(base + p) * 64 + c] = mx;
        }
    }
}

// ---------------- K4: out = lrelu((out - mean3) * rstd3), in place ----------------
__global__ __launch_bounds__(256) void k4_final(float* __restrict__ out,
        const float* __restrict__ s3) {
    int idx = blockIdx.x * 256 + threadIdx.x;
    int c = idx & 63;
    int b = idx >> 18;               // 4096*64 = 2^18 per batch
    const float inv = 1.0f / (float)NKCNT;
    float mm = s3[b * 64 + c] * inv;
    float vv = s3[512 + b * 64 + c] * inv - mm * mm;
    float r = rsqrtf(vv + EPSI);
    float val = (out[idx] - mm) * r;
    out[idx] = val >= 0.f ? val : SLOPE * val;
}

extern "C" void kernel_launch(void* const* d_in, const int* in_sizes, int n_in,
                              void* d_out, int out_size, void* d_ws, size_t ws_size,
                              hipStream_t stream) {
    const float* x   = (const float*)d_in[0];
    const int*   ind = (const int*)d_in[1];
    const float* W1  = (const float*)d_in[2];
    const float* W2  = (const float*)d_in[3];
    const float* W3  = (const float*)d_in[4];
    float* out = (float*)d_out;

    unsigned short* u = (unsigned short*)d_ws;            // [32768][64] bf16
    unsigned short* v = u + BN * 64;                      // [32768][64] bf16
    float* stats = (float*)(v + BN * 64);
    float* s1 = stats;          // [2][512]
    float* s2 = stats + 1024;   // [2][512]
    float* s3 = stats + 2048;   // [2][512]

    hipMemsetAsync(stats, 0, 3 * 1024 * sizeof(float), stream);
    k0_uv<<<dim3(BN / 16), dim3(256), 0, stream>>>(x, W1, u, v);
    k1_stats1<<<dim3(BDIM * NPTS / 16), dim3(256), 0, stream>>>(u, v, ind, s1);
    k2_stats2<<<dim3(BDIM * NPTS / 16), dim3(256), 0, stream>>>(u, v, ind, W2, s1, s2);
    k3_main<<<dim3(BDIM * NPTS / 16), dim3(256), 0, stream>>>(u, v, ind, W2, W3, s1, s2, s3, out);
    k4_final<<<dim3(BDIM * NPTS * 64 / 256), dim3(256), 0, stream>>>(out, s3);
}

// Round 2
// 217.683 us; speedup vs baseline: 1.2301x; 1.2301x over previous
//
#include <hip/hip_runtime.h>

#define BDIM 8
#define NPTS 4096
#define KNEI 20
#define BN (BDIM*NPTS)        // 32768
#define NKCNT (NPTS*KNEI)     // 81920
#define EPSI 1e-5f
#define SLOPE 0.01f

typedef __attribute__((ext_vector_type(8))) short bf16x8;
typedef __attribute__((ext_vector_type(4))) float f32x4;

__device__ __forceinline__ unsigned short f2bf(float f) {
    unsigned u = __builtin_bit_cast(unsigned, f);
    u += 0x7FFFu + ((u >> 16) & 1u);
    return (unsigned short)(u >> 16);
}
__device__ __forceinline__ float bf2f(unsigned short h) {
    unsigned u = ((unsigned)h) << 16;
    return __builtin_bit_cast(float, u);
}

// ---------------- K0: u = x*W1a^T, v = x*(W1b-W1a)^T  (bf16 out) ----------------
__global__ __launch_bounds__(256) void k0_uv(const float* __restrict__ x,
        const float* __restrict__ W1, unsigned short* __restrict__ u,
        unsigned short* __restrict__ v) {
    __shared__ float wlds[64 * 129];     // W1 [64][128] padded stride 129
    __shared__ float xs[16 * 64];
    int tid = threadIdx.x;
    int m0 = blockIdx.x * 16;
    for (int i = tid; i < 8192; i += 256)
        wlds[(i >> 7) * 129 + (i & 127)] = W1[i];
    for (int i = tid; i < 1024; i += 256)
        xs[i] = x[m0 * 64 + i];
    __syncthreads();
    int o = tid & 63;
    int r0 = tid >> 6;   // 0..3
    float au[4] = {0.f, 0.f, 0.f, 0.f};
    float av[4] = {0.f, 0.f, 0.f, 0.f};
    for (int c = 0; c < 64; ++c) {
        float wa = wlds[o * 129 + c];
        float wb = wlds[o * 129 + 64 + c];
        float wd = wb - wa;
#pragma unroll
        for (int jj = 0; jj < 4; ++jj) {
            float xv = xs[(r0 + jj * 4) * 64 + c];
            au[jj] += xv * wa;
            av[jj] += xv * wd;
        }
    }
#pragma unroll
    for (int jj = 0; jj < 4; ++jj) {
        int m = m0 + r0 + jj * 4;
        u[m * 64 + o] = f2bf(au[jj]);
        v[m * 64 + o] = f2bf(av[jj]);
    }
}

// ------- K1: stats1 (sum, sumsq of h1 = u[ind]+v) per (b,c); optional h1 store -------
__global__ __launch_bounds__(256) void k1_stats1(const unsigned short* __restrict__ u,
        const unsigned short* __restrict__ v, const int* __restrict__ ind,
        float* __restrict__ s1, unsigned short* __restrict__ h1g) {
    __shared__ int ind_s[320];
    __shared__ unsigned short vs[1024];
    __shared__ float part[256 * 4];
    int tid = threadIdx.x;
    int b = blockIdx.x >> 8;             // 256 blocks per batch
    int n0 = (blockIdx.x & 255) << 4;
    int base = b * NPTS + n0;
    int base20 = base * 20;
    for (int i = tid; i < 320; i += 256) ind_s[i] = ind[base20 + i];
    for (int i = tid; i < 1024; i += 256) vs[i] = v[base * 64 + i];
    __syncthreads();
    int c2 = (tid & 31) * 2;
    int rr = tid >> 5;
    float sA = 0.f, qA = 0.f, sB = 0.f, qB = 0.f;
    for (int j = 0; j < 40; ++j) {
        int r = rr + j * 8;
        int idx = ind_s[r];
        int p = r / 20;
        unsigned uu = *(const unsigned*)(u + idx * 64 + c2);
        float h0 = bf2f((unsigned short)(uu & 0xFFFF)) + bf2f(vs[p * 64 + c2]);
        float h1 = bf2f((unsigned short)(uu >> 16)) + bf2f(vs[p * 64 + c2 + 1]);
        sA += h0; qA += h0 * h0;
        sB += h1; qB += h1 * h1;
        if (h1g)
            *(unsigned*)&h1g[(base20 + r) * 64 + c2] =
                (unsigned)f2bf(h0) | ((unsigned)f2bf(h1) << 16);
    }
    part[tid * 4 + 0] = sA; part[tid * 4 + 1] = qA;
    part[tid * 4 + 2] = sB; part[tid * 4 + 3] = qB;
    __syncthreads();
    if (tid < 128) {
        int c = tid & 63, st = tid >> 6;
        float acc = 0.f;
        for (int g = 0; g < 8; ++g)
            acc += part[(g * 32 + (c >> 1)) * 4 + (c & 1) * 2 + st];
        atomicAdd(&s1[st * 512 + b * 64 + c], acc);
    }
}

// ---- helper: load B-fragments (W row-major [64][64] fp32 -> bf16 frags) ----
__device__ __forceinline__ void load_bfrags(const float* __restrict__ W,
        int l15, int q, bf16x8 bw[4][2]) {
#pragma unroll
    for (int nt = 0; nt < 4; ++nt)
#pragma unroll
        for (int ks = 0; ks < 2; ++ks) {
            const float* wp = W + (nt * 16 + l15) * 64 + ks * 32 + q * 8;
            bf16x8 t;
#pragma unroll
            for (int j = 0; j < 8; ++j) t[j] = (short)f2bf(wp[j]);
            bw[nt][ks] = t;
        }
}

// ---- helper: in-register instancenorm + leaky relu on a bf16x8 fragment ----
__device__ __forceinline__ bf16x8 norm_act(bf16x8 raw, const float* m, const float* r) {
    bf16x8 o;
#pragma unroll
    for (int j = 0; j < 8; ++j) {
        float f = bf2f((unsigned short)raw[j]);
        float t = (f - m[j]) * r[j];
        t = t >= 0.f ? t : SLOPE * t;
        o[j] = (short)f2bf(t);
    }
    return o;
}

// ---------------- K2 (streaming): h1 -> norm1+lrelu -> GEMM2 -> h2, stats2 ----------------
__global__ __launch_bounds__(256) void k2_gemm2(const unsigned short* __restrict__ h1g,
        const float* __restrict__ W2, const float* __restrict__ s1,
        float* __restrict__ s2, unsigned short* __restrict__ h2g) {
    __shared__ float part[2048];
    int tid = threadIdx.x;
    int b = blockIdx.x >> 8;
    int n0 = (blockIdx.x & 255) << 4;
    int base20 = (b * NPTS + n0) * 20;
    int lane = tid & 63, w = tid >> 6;
    int l15 = lane & 15, q = lane >> 4;
    const float inv = 1.0f / (float)NKCNT;
    // norm1 params for this lane's A-fragment channels: c = ks*32 + q*8 + j
    float m1[2][8], r1[2][8];
#pragma unroll
    for (int ks = 0; ks < 2; ++ks)
#pragma unroll
        for (int j = 0; j < 8; ++j) {
            int c = ks * 32 + q * 8 + j;
            float mm = s1[b * 64 + c] * inv;
            float vv = s1[512 + b * 64 + c] * inv - mm * mm;
            m1[ks][j] = mm;
            r1[ks][j] = rsqrtf(vv + EPSI);
        }
    bf16x8 bw[4][2];
    load_bfrags(W2, l15, q, bw);
    float ss[4] = {0.f, 0.f, 0.f, 0.f}, qq[4] = {0.f, 0.f, 0.f, 0.f};
#pragma unroll
    for (int mt = 0; mt < 5; ++mt) {
        int row = (w * 5 + mt) * 16 + l15;
        const unsigned short* hp = h1g + (base20 + row) * 64;
        bf16x8 raw0 = *(const bf16x8*)(hp + q * 8);
        bf16x8 raw1 = *(const bf16x8*)(hp + 32 + q * 8);
        bf16x8 a0 = norm_act(raw0, m1[0], r1[0]);
        bf16x8 a1 = norm_act(raw1, m1[1], r1[1]);
        f32x4 acc[4];
#pragma unroll
        for (int nt = 0; nt < 4; ++nt) acc[nt] = (f32x4){0.f, 0.f, 0.f, 0.f};
#pragma unroll
        for (int nt = 0; nt < 4; ++nt) {
            acc[nt] = __builtin_amdgcn_mfma_f32_16x16x32_bf16(a0, bw[nt][0], acc[nt], 0, 0, 0);
            acc[nt] = __builtin_amdgcn_mfma_f32_16x16x32_bf16(a1, bw[nt][1], acc[nt], 0, 0, 0);
        }
        // consume: stats2 partials + store h2 (row-major bf16, C-layout scatter)
        int rb = base20 + (w * 5 + mt) * 16 + q * 4;
#pragma unroll
        for (int nt = 0; nt < 4; ++nt)
#pragma unroll
            for (int i = 0; i < 4; ++i) {
                float d = acc[nt][i];
                ss[nt] += d; qq[nt] += d * d;
                h2g[(rb + i) * 64 + nt * 16 + l15] = f2bf(d);
            }
    }
#pragma unroll
    for (int nt = 0; nt < 4; ++nt) {
        int pi = (((w * 4 + nt) * 4 + q) * 16 + l15) * 2;
        part[pi] = ss[nt]; part[pi + 1] = qq[nt];
    }
    __syncthreads();
    if (tid < 128) {
        int c = tid & 63, st = tid >> 6;
        int nt = c >> 4, cl = c & 15;
        float a = 0.f;
        for (int ww = 0; ww < 4; ++ww)
            for (int q2 = 0; q2 < 4; ++q2)
                a += part[(((ww * 4 + nt) * 4 + q2) * 16 + cl) * 2 + st];
        atomicAdd(&s2[st * 512 + b * 64 + c], a);
    }
}

// ----- K3 (streaming): h2 -> norm2+lrelu -> GEMM3 -> stats3 + shfl-max over k -> out -----
__global__ __launch_bounds__(256) void k3_gemm3(const unsigned short* __restrict__ h2g,
        const float* __restrict__ W3, const float* __restrict__ s2,
        float* __restrict__ s3, float* __restrict__ out) {
    __shared__ float part[2048];
    int tid = threadIdx.x;
    int b = blockIdx.x >> 8;
    int n0 = (blockIdx.x & 255) << 4;
    int base = b * NPTS + n0;
    int base20 = base * 20;
    int lane = tid & 63, w = tid >> 6;
    int l15 = lane & 15, q = lane >> 4;
    const float inv = 1.0f / (float)NKCNT;
    float m2[2][8], r2[2][8];
#pragma unroll
    for (int ks = 0; ks < 2; ++ks)
#pragma unroll
        for (int j = 0; j < 8; ++j) {
            int c = ks * 32 + q * 8 + j;
            float mm = s2[b * 64 + c] * inv;
            float vv = s2[512 + b * 64 + c] * inv - mm * mm;
            m2[ks][j] = mm;
            r2[ks][j] = rsqrtf(vv + EPSI);
        }
    bf16x8 bw[4][2];
    load_bfrags(W3, l15, q, bw);
    float ss[4] = {0.f, 0.f, 0.f, 0.f}, qq[4] = {0.f, 0.f, 0.f, 0.f};
    float pmax[4][4];
#pragma unroll
    for (int nt = 0; nt < 4; ++nt)
#pragma unroll
        for (int pp = 0; pp < 4; ++pp) pmax[nt][pp] = -3.4e38f;
#pragma unroll
    for (int mt = 0; mt < 5; ++mt) {
        int row = (w * 5 + mt) * 16 + l15;
        const unsigned short* hp = h2g + (base20 + row) * 64;
        bf16x8 raw0 = *(const bf16x8*)(hp + q * 8);
        bf16x8 raw1 = *(const bf16x8*)(hp + 32 + q * 8);
        bf16x8 a0 = norm_act(raw0, m2[0], r2[0]);
        bf16x8 a1 = norm_act(raw1, m2[1], r2[1]);
        f32x4 acc[4];
#pragma unroll
        for (int nt = 0; nt < 4; ++nt) acc[nt] = (f32x4){0.f, 0.f, 0.f, 0.f};
#pragma unroll
        for (int nt = 0; nt < 4; ++nt) {
            acc[nt] = __builtin_amdgcn_mfma_f32_16x16x32_bf16(a0, bw[nt][0], acc[nt], 0, 0, 0);
            acc[nt] = __builtin_amdgcn_mfma_f32_16x16x32_bf16(a1, bw[nt][1], acc[nt], 0, 0, 0);
        }
        // consume: stats3 partials + per-point running max (pre-norm h3)
#pragma unroll
        for (int i = 0; i < 4; ++i) {
            int rloc = mt * 16 + q * 4 + i;          // 0..79 within wave's 4 points
            int p = (rloc >= 60) ? 3 : (rloc >= 40) ? 2 : (rloc >= 20) ? 1 : 0;
#pragma unroll
            for (int nt = 0; nt < 4; ++nt) {
                float d = acc[nt][i];
                ss[nt] += d; qq[nt] += d * d;
#pragma unroll
                for (int pp = 0; pp < 4; ++pp)
                    if (p == pp) pmax[nt][pp] = fmaxf(pmax[nt][pp], d);
            }
        }
    }
#pragma unroll
    for (int nt = 0; nt < 4; ++nt) {
        int pi = (((w * 4 + nt) * 4 + q) * 16 + l15) * 2;
        part[pi] = ss[nt]; part[pi + 1] = qq[nt];
    }
    __syncthreads();
    if (tid < 128) {
        int c = tid & 63, st = tid >> 6;
        int nt = c >> 4, cl = c & 15;
        float a = 0.f;
        for (int ww = 0; ww < 4; ++ww)
            for (int q2 = 0; q2 < 4; ++q2)
                a += part[(((ww * 4 + nt) * 4 + q2) * 16 + cl) * 2 + st];
        atomicAdd(&s3[st * 512 + b * 64 + c], a);
    }
    // cross-q max combine (each q lane held 5 of each point's 20 rows)
#pragma unroll
    for (int nt = 0; nt < 4; ++nt)
#pragma unroll
        for (int pp = 0; pp < 4; ++pp) {
            float vv = pmax[nt][pp];
            vv = fmaxf(vv, __shfl_xor(vv, 16, 64));
            vv = fmaxf(vv, __shfl_xor(vv, 32, 64));
            pmax[nt][pp] = vv;
        }
    // lane (l15, q) stores point (w*4 + q), channels nt*16 + l15 (pre-norm max)
    int ptg = base + w * 4 + q;
#pragma unroll
    for (int nt = 0; nt < 4; ++nt) {
        float vq = (q == 0) ? pmax[nt][0] : (q == 1) ? pmax[nt][1]
                 : (q == 2) ? pmax[nt][2] : pmax[nt][3];
        out[ptg * 64 + nt * 16 + l15] = vq;
    }
}

// ---------------- K4: out = lrelu((out - mean3) * rstd3), in place ----------------
__global__ __launch_bounds__(256) void k4_final(float* __restrict__ out,
        const float* __restrict__ s3) {
    int idx = blockIdx.x * 256 + threadIdx.x;
    int c = idx & 63;
    int b = idx >> 18;               // 4096*64 = 2^18 per batch
    const float inv = 1.0f / (float)NKCNT;
    float mm = s3[b * 64 + c] * inv;
    float vv = s3[512 + b * 64 + c] * inv - mm * mm;
    float r = rsqrtf(vv + EPSI);
    float val = (out[idx] - mm) * r;
    out[idx] = val >= 0.f ? val : SLOPE * val;
}

// ======================= fallback path (round-1 kernels) =======================
#define ASTR 72

union ShrU {
    struct { int ind_s[320]; unsigned short vs[1024]; } st;
    float part[2048];
};

__device__ __forceinline__ void stage_a1(unsigned short* bufA, ShrU& shr,
        const unsigned short* __restrict__ u, const unsigned short* __restrict__ v,
        const int* __restrict__ ind, const float* __restrict__ s1,
        int b, int base, int tid) {
    for (int i = tid; i < 320; i += 256) shr.st.ind_s[i] = ind[base * 20 + i];
    for (int i = tid; i < 1024; i += 256) shr.st.vs[i] = v[base * 64 + i];
    int c2 = (tid & 31) * 2;
    const float inv = 1.0f / (float)NKCNT;
    float m1a = s1[b * 64 + c2] * inv;
    float m1b = s1[b * 64 + c2 + 1] * inv;
    float v1a = s1[512 + b * 64 + c2] * inv - m1a * m1a;
    float v1b = s1[512 + b * 64 + c2 + 1] * inv - m1b * m1b;
    float r1a = rsqrtf(v1a + EPSI), r1b = rsqrtf(v1b + EPSI);
    __syncthreads();
    int rr = tid >> 5;
    for (int j = 0; j < 40; ++j) {
        int r = rr + j * 8;
        int idx = shr.st.ind_s[r];
        int p = r / 20;
        unsigned uu = *(const unsigned*)(u + idx * 64 + c2);
        float h0 = bf2f((unsigned short)(uu & 0xFFFF)) + bf2f(shr.st.vs[p * 64 + c2]);
        float h1 = bf2f((unsigned short)(uu >> 16)) + bf2f(shr.st.vs[p * 64 + c2 + 1]);
        float a0 = (h0 - m1a) * r1a; a0 = a0 >= 0.f ? a0 : SLOPE * a0;
        float a1 = (h1 - m1b) * r1b; a1 = a1 >= 0.f ? a1 : SLOPE * a1;
        unsigned pk = (unsigned)f2bf(a0) | ((unsigned)f2bf(a1) << 16);
        *(unsigned*)&bufA[r * ASTR + c2] = pk;
    }
    __syncthreads();
}

__global__ __launch_bounds__(256) void k2_stats2_fb(const unsigned short* __restrict__ u,
        const unsigned short* __restrict__ v, const int* __restrict__ ind,
        const float* __restrict__ W2, const float* __restrict__ s1,
        float* __restrict__ s2) {
    __shared__ unsigned short bufA[320 * ASTR];
    __shared__ ShrU shr;
    int tid = threadIdx.x;
    int b = blockIdx.x >> 8;
    int n0 = (blockIdx.x & 255) << 4;
    int base = b * NPTS + n0;
    stage_a1(bufA, shr, u, v, ind, s1, b, base, tid);
    int lane = tid & 63, w = tid >> 6;
    int l15 = lane & 15, q = lane >> 4;
    bf16x8 bw[4][2];
    load_bfrags(W2, l15, q, bw);
    f32x4 acc[5][4];
#pragma unroll
    for (int mt = 0; mt < 5; ++mt)
#pragma unroll
        for (int nt = 0; nt < 4; ++nt) acc[mt][nt] = (f32x4){0.f, 0.f, 0.f, 0.f};
#pragma unroll
    for (int mt = 0; mt < 5; ++mt) {
        int row = (w * 5 + mt) * 16 + l15;
        bf16x8 a0 = *(bf16x8*)&bufA[row * ASTR + q * 8];
        bf16x8 a1 = *(bf16x8*)&bufA[row * ASTR + 32 + q * 8];
#pragma unroll
        for (int nt = 0; nt < 4; ++nt) {
            acc[mt][nt] = __builtin_amdgcn_mfma_f32_16x16x32_bf16(a0, bw[nt][0], acc[mt][nt], 0, 0, 0);
            acc[mt][nt] = __builtin_amdgcn_mfma_f32_16x16x32_bf16(a1, bw[nt][1], acc[mt][nt], 0, 0, 0);
        }
    }
#pragma unroll
    for (int nt = 0; nt < 4; ++nt) {
        float ssv = 0.f, qqv = 0.f;
#pragma unroll
        for (int mt = 0; mt < 5; ++mt)
#pragma unroll
            for (int i = 0; i < 4; ++i) { float d = acc[mt][nt][i]; ssv += d; qqv += d * d; }
        int pi = (((w * 4 + nt) * 4 + q) * 16 + l15) * 2;
        shr.part[pi] = ssv; shr.part[pi + 1] = qqv;
    }
    __syncthreads();
    if (tid < 128) {
        int c = tid & 63, st = tid >> 6;
        int nt = c >> 4, cl = c & 15;
        float a = 0.f;
        for (int ww = 0; ww < 4; ++ww)
            for (int q2 = 0; q2 < 4; ++q2)
                a += shr.part[(((ww * 4 + nt) * 4 + q2) * 16 + cl) * 2 + st];
        atomicAdd(&s2[st * 512 + b * 64 + c], a);
    }
}

__global__ __launch_bounds__(256) void k3_main_fb(const unsigned short* __restrict__ u,
        const unsigned short* __restrict__ v, const int* __restrict__ ind,
        const float* __restrict__ W2, const float* __restrict__ W3,
        const float* __restrict__ s1, const float* __restrict__ s2,
        float* __restrict__ s3, float* __restrict__ out) {
    __shared__ unsigned short bufA[320 * ASTR];
    __shared__ ShrU shr;
    int tid = threadIdx.x;
    int b = blockIdx.x >> 8;
    int n0 = (blockIdx.x & 255) << 4;
    int base = b * NPTS + n0;
    stage_a1(bufA, shr, u, v, ind, s1, b, base, tid);
    int lane = tid & 63, w = tid >> 6;
    int l15 = lane & 15, q = lane >> 4;
    const float inv = 1.0f / (float)NKCNT;
    float m2[4], r2[4];
#pragma unroll
    for (int nt = 0; nt < 4; ++nt) {
        int c = nt * 16 + l15;
        float mm = s2[b * 64 + c] * inv;
        float vv = s2[512 + b * 64 + c] * inv - mm * mm;
        m2[nt] = mm; r2[nt] = rsqrtf(vv + EPSI);
    }
    bf16x8 bw[4][2];
    load_bfrags(W2, l15, q, bw);
    f32x4 acc[5][4];
#pragma unroll
    for (int mt = 0; mt < 5; ++mt)
#pragma unroll
        for (int nt = 0; nt < 4; ++nt) acc[mt][nt] = (f32x4){0.f, 0.f, 0.f, 0.f};
#pragma unroll
    for (int mt = 0; mt < 5; ++mt) {
        int row = (w * 5 + mt) * 16 + l15;
        bf16x8 a0 = *(bf16x8*)&bufA[row * ASTR + q * 8];
        bf16x8 a1 = *(bf16x8*)&bufA[row * ASTR + 32 + q * 8];
#pragma unroll
        for (int nt = 0; nt < 4; ++nt) {
            acc[mt][nt] = __builtin_amdgcn_mfma_f32_16x16x32_bf16(a0, bw[nt][0], acc[mt][nt], 0, 0, 0);
            acc[mt][nt] = __builtin_amdgcn_mfma_f32_16x16x32_bf16(a1, bw[nt][1], acc[mt][nt], 0, 0, 0);
        }
    }
#pragma unroll
    for (int mt = 0; mt < 5; ++mt)
#pragma unroll
        for (int nt = 0; nt < 4; ++nt)
#pragma unroll
            for (int i = 0; i < 4; ++i) {
                float a = (acc[mt][nt][i] - m2[nt]) * r2[nt];
                a = a >= 0.f ? a : SLOPE * a;
                int row = (w * 5 + mt) * 16 + q * 4 + i;
                bufA[row * ASTR + nt * 16 + l15] = f2bf(a);
            }
    load_bfrags(W3, l15, q, bw);
#pragma unroll
    for (int mt = 0; mt < 5; ++mt)
#pragma unroll
        for (int nt = 0; nt < 4; ++nt) acc[mt][nt] = (f32x4){0.f, 0.f, 0.f, 0.f};
#pragma unroll
    for (int mt = 0; mt < 5; ++mt) {
        int row = (w * 5 + mt) * 16 + l15;
        bf16x8 a0 = *(bf16x8*)&bufA[row * ASTR + q * 8];
        bf16x8 a1 = *(bf16x8*)&bufA[row * ASTR + 32 + q * 8];
#pragma unroll
        for (int nt = 0; nt < 4; ++nt) {
            acc[mt][nt] = __builtin_amdgcn_mfma_f32_16x16x32_bf16(a0, bw[nt][0], acc[mt][nt], 0, 0, 0);
            acc[mt][nt] = __builtin_amdgcn_mfma_f32_16x16x32_bf16(a1, bw[nt][1], acc[mt][nt], 0, 0, 0);
        }
    }
#pragma unroll
    for (int nt = 0; nt < 4; ++nt) {
        float ssv = 0.f, qqv = 0.f;
#pragma unroll
        for (int mt = 0; mt < 5; ++mt)
#pragma unroll
            for (int i = 0; i < 4; ++i) {
                float d = acc[mt][nt][i];
                ssv += d; qqv += d * d;
                int row = (w * 5 + mt) * 16 + q * 4 + i;
                bufA[row * ASTR + nt * 16 + l15] = f2bf(d);
            }
        int pi = (((w * 4 + nt) * 4 + q) * 16 + l15) * 2;
        shr.part[pi] = ssv; shr.part[pi + 1] = qqv;
    }
    __syncthreads();
    if (tid < 128) {
        int c = tid & 63, st = tid >> 6;
        int nt = c >> 4, cl = c & 15;
        float a = 0.f;
        for (int ww = 0; ww < 4; ++ww)
            for (int q2 = 0; q2 < 4; ++q2)
                a += shr.part[(((ww * 4 + nt) * 4 + q2) * 16 + cl) * 2 + st];
        atomicAdd(&s3[st * 512 + b * 64 + c], a);
    }
    {
        int c = tid & 63;
        int p0 = tid >> 6;
#pragma unroll
        for (int ii = 0; ii < 4; ++ii) {
            int p = p0 * 4 + ii;
            float mx = -3.4e38f;
            for (int kk = 0; kk < 20; ++kk)
                mx = fmaxf(mx, bf2f(bufA[(p * 20 + kk) * ASTR + c]));
            out[(base + p) * 64 + c] = mx;
        }
    }
}

// ==============================================================================

extern "C" void kernel_launch(void* const* d_in, const int* in_sizes, int n_in,
                              void* d_out, int out_size, void* d_ws, size_t ws_size,
                              hipStream_t stream) {
    const float* x   = (const float*)d_in[0];
    const int*   ind = (const int*)d_in[1];
    const float* W1  = (const float*)d_in[2];
    const float* W2  = (const float*)d_in[3];
    const float* W3  = (const float*)d_in[4];
    float* out = (float*)d_out;

    unsigned short* u = (unsigned short*)d_ws;            // [32768][64] bf16
    unsigned short* v = u + BN * 64;                      // [32768][64] bf16
    float* stats = (float*)(v + BN * 64);
    float* s1 = stats;          // [2][512]
    float* s2 = stats + 1024;   // [2][512]
    float* s3 = stats + 2048;   // [2][512]
    unsigned short* h1 = (unsigned short*)(stats + 3 * 1024);  // [BN*20][64] bf16
    unsigned short* h2 = h1 + (size_t)BN * 20 * 64;            // [BN*20][64] bf16

    size_t need_full = (size_t)BN * 64 * 2 * 2            // u, v
                     + 3 * 1024 * 4                       // stats
                     + (size_t)BN * 20 * 64 * 2 * 2;      // h1, h2

    hipMemsetAsync(stats, 0, 3 * 1024 * sizeof(float), stream);
    k0_uv<<<dim3(BN / 16), dim3(256), 0, stream>>>(x, W1, u, v);

    if (ws_size >= need_full) {
        k1_stats1<<<dim3(BN / 16), dim3(256), 0, stream>>>(u, v, ind, s1, h1);
        k2_gemm2<<<dim3(BN / 16), dim3(256), 0, stream>>>(h1, W2, s1, s2, h2);
        k3_gemm3<<<dim3(BN / 16), dim3(256), 0, stream>>>(h2, W3, s2, s3, out);
    } else {
        k1_stats1<<<dim3(BN / 16), dim3(256), 0, stream>>>(u, v, ind, s1, nullptr);
        k2_stats2_fb<<<dim3(BN / 16), dim3(256), 0, stream>>>(u, v, ind, W2, s1, s2);
        k3_main_fb<<<dim3(BN / 16), dim3(256), 0, stream>>>(u, v, ind, W2, W3, s1, s2, s3, out);
    }
    k4_final<<<dim3(BN * 64 / 256), dim3(256), 0, stream>>>(out, s3);
}

// Round 3
// 213.093 us; speedup vs baseline: 1.2566x; 1.0215x over previous
//
#include <hip/hip_runtime.h>

#define BDIM 8
#define NPTS 4096
#define KNEI 20
#define BN (BDIM*NPTS)        // 32768
#define NKCNT (NPTS*KNEI)     // 81920
#define EPSI 1e-5f
#define SLOPE 0.01f

typedef __attribute__((ext_vector_type(8))) short bf16x8;
typedef __attribute__((ext_vector_type(4))) float f32x4;
typedef __attribute__((ext_vector_type(4))) unsigned int u32x4;

__device__ __forceinline__ unsigned short f2bf(float f) {
    unsigned u = __builtin_bit_cast(unsigned, f);
    u += 0x7FFFu + ((u >> 16) & 1u);
    return (unsigned short)(u >> 16);
}
__device__ __forceinline__ float bf2f(unsigned short h) {
    unsigned u = ((unsigned)h) << 16;
    return __builtin_bit_cast(float, u);
}

// async global->LDS DMA, 16 B per lane; LDS dest = wave-uniform base + lane*16,
// global src = per-lane address (supports gather).
__device__ __forceinline__ void async16(const void* g, void* l) {
    __builtin_amdgcn_global_load_lds(
        (const __attribute__((address_space(1))) unsigned int*)g,
        (__attribute__((address_space(3))) unsigned int*)l, 16, 0, 0);
}

// ---------------- K0: u = x*W1a^T, v = x*(W1b-W1a)^T  (bf16 out) ----------------
__global__ __launch_bounds__(256) void k0_uv(const float* __restrict__ x,
        const float* __restrict__ W1, unsigned short* __restrict__ u,
        unsigned short* __restrict__ v) {
    __shared__ float wlds[64 * 129];
    __shared__ float xs[16 * 64];
    int tid = threadIdx.x;
    int m0 = blockIdx.x * 16;
    for (int i = tid; i < 8192; i += 256)
        wlds[(i >> 7) * 129 + (i & 127)] = W1[i];
    for (int i = tid; i < 1024; i += 256)
        xs[i] = x[m0 * 64 + i];
    __syncthreads();
    int o = tid & 63;
    int r0 = tid >> 6;
    float au[4] = {0.f, 0.f, 0.f, 0.f};
    float av[4] = {0.f, 0.f, 0.f, 0.f};
    for (int c = 0; c < 64; ++c) {
        float wa = wlds[o * 129 + c];
        float wb = wlds[o * 129 + 64 + c];
        float wd = wb - wa;
#pragma unroll
        for (int jj = 0; jj < 4; ++jj) {
            float xv = xs[(r0 + jj * 4) * 64 + c];
            au[jj] += xv * wa;
            av[jj] += xv * wd;
        }
    }
#pragma unroll
    for (int jj = 0; jj < 4; ++jj) {
        int m = m0 + r0 + jj * 4;
        u[m * 64 + o] = f2bf(au[jj]);
        v[m * 64 + o] = f2bf(av[jj]);
    }
}

// ---- helper: load A-fragments (W row-major [64][64] fp32 -> bf16 frags) ----
// A[m=lane&15][k=q*8+j] = W[mtile*16+l15][kc*32+q*8+j]
__device__ __forceinline__ void load_bfrags(const float* __restrict__ W,
        int l15, int q, bf16x8 bw[4][2]) {
#pragma unroll
    for (int mt = 0; mt < 4; ++mt)
#pragma unroll
        for (int kc = 0; kc < 2; ++kc) {
            const float* wp = W + (mt * 16 + l15) * 64 + kc * 32 + q * 8;
            bf16x8 t;
#pragma unroll
            for (int j = 0; j < 8; ++j) t[j] = (short)f2bf(wp[j]);
            bw[mt][kc] = t;
        }
}

// ---------------- K1: stats1 of h1 = u[ind]+v, via DMA-gathered LDS tile ----------------
__global__ __launch_bounds__(256) void k1_stats1(const unsigned short* __restrict__ u,
        const unsigned short* __restrict__ v, const int* __restrict__ ind,
        float* __restrict__ s1) {
    __shared__ __align__(16) unsigned char tile[40960];   // 320 rows x 128 B (swizzled)
    __shared__ __align__(16) unsigned char vt[2048];      // 16 rows x 128 B (identity)
    __shared__ int inds[320];
    __shared__ float part[1024];
    int tid = threadIdx.x;
    int lane = tid & 63, w = tid >> 6;
    int b = blockIdx.x >> 8;
    int n0 = (blockIdx.x & 255) << 4;
    int base = b * NPTS + n0;
    int base20 = base * 20;
    for (int i = tid; i < 320; i += 256) inds[i] = ind[base20 + i];
    if (w == 0) {
#pragma unroll
        for (int k = 0; k < 2; ++k)
            async16(v + (size_t)(base + 8 * k + (lane >> 3)) * 64 + (lane & 7) * 8,
                    vt + k * 1024);
    }
    __syncthreads();
    int swz = (lane & 7) ^ ((lane >> 3) & 7);
#pragma unroll
    for (int j = 0; j < 10; ++j) {
        int k = w * 10 + j;
        int r = 8 * k + (lane >> 3);
        int idx = inds[r];
        async16(u + (size_t)idx * 64 + swz * 8, tile + k * 1024);
    }
    __syncthreads();
    int c2 = (tid & 31) * 2;
    int rr = tid >> 5;                       // 0..7, == row&7 for all its rows
    int uoff = (((c2 >> 3) ^ rr) << 4) + ((c2 * 2) & 15);
    float sA = 0.f, qA = 0.f, sB = 0.f, qB = 0.f;
    for (int j = 0; j < 40; ++j) {
        int r = rr + 8 * j;
        int p = (r * 3277) >> 16;            // r/20 for r<320
        unsigned uu = *(const unsigned*)(tile + r * 128 + uoff);
        unsigned vv = *(const unsigned*)(vt + p * 128 + c2 * 2);
        float h0 = bf2f((unsigned short)(uu & 0xFFFF)) + bf2f((unsigned short)(vv & 0xFFFF));
        float h1 = bf2f((unsigned short)(uu >> 16)) + bf2f((unsigned short)(vv >> 16));
        sA += h0; qA += h0 * h0;
        sB += h1; qB += h1 * h1;
    }
    part[tid * 4 + 0] = sA; part[tid * 4 + 1] = qA;
    part[tid * 4 + 2] = sB; part[tid * 4 + 3] = qB;
    __syncthreads();
    if (tid < 128) {
        int c = tid & 63, st = tid >> 6;
        float acc = 0.f;
        for (int g = 0; g < 8; ++g)
            acc += part[(g * 32 + (c >> 1)) * 4 + (c & 1) * 2 + st];
        atomicAdd(&s1[st * 512 + b * 64 + c], acc);
    }
}

// ------ K2: gather u[ind]+v -> norm1+lrelu -> GEMM2 (A=W2, C=h2^T) -> h2 tile + stats2 ------
__global__ __launch_bounds__(256) void k2_gemm2(const unsigned short* __restrict__ u,
        const unsigned short* __restrict__ v, const int* __restrict__ ind,
        const float* __restrict__ W2, const float* __restrict__ s1,
        float* __restrict__ s2, unsigned short* __restrict__ h2g) {
    __shared__ __align__(16) unsigned char tile[40960];
    __shared__ __align__(16) unsigned char vt[2048];
    __shared__ int inds[320];
    __shared__ float red[512];
    int tid = threadIdx.x;
    int lane = tid & 63, w = tid >> 6;
    int l15 = lane & 15, q = lane >> 4;
    int b = blockIdx.x >> 8;
    int n0 = (blockIdx.x & 255) << 4;
    int base = b * NPTS + n0;
    int base20 = base * 20;
    // early independent loads: W2 A-frags + norm1 params
    bf16x8 aw[4][2];
    load_bfrags(W2, l15, q, aw);
    const float inv = 1.0f / (float)NKCNT;
    float r1[2][8], mr1[2][8];
#pragma unroll
    for (int kc = 0; kc < 2; ++kc)
#pragma unroll
        for (int j = 0; j < 8; ++j) {
            int c = kc * 32 + q * 8 + j;
            float mm = s1[b * 64 + c] * inv;
            float vv = s1[512 + b * 64 + c] * inv - mm * mm;
            float rs = rsqrtf(vv + EPSI);
            r1[kc][j] = rs; mr1[kc][j] = -mm * rs;
        }
    for (int i = tid; i < 320; i += 256) inds[i] = ind[base20 + i];
    if (w == 0) {
#pragma unroll
        for (int k = 0; k < 2; ++k)
            async16(v + (size_t)(base + 8 * k + (lane >> 3)) * 64 + (lane & 7) * 8,
                    vt + k * 1024);
    }
    __syncthreads();
    int swz = (lane & 7) ^ ((lane >> 3) & 7);
#pragma unroll
    for (int j = 0; j < 10; ++j) {
        int k = w * 10 + j;
        int r = 8 * k + (lane >> 3);
        int idx = inds[r];
        async16(u + (size_t)idx * 64 + swz * 8, tile + k * 1024);
    }
    __syncthreads();
    // preload B-frags: a1 rows, normalized+activated
    bf16x8 bf[5][2];
#pragma unroll
    for (int nt = 0; nt < 5; ++nt) {
        int row = (w * 5 + nt) * 16 + l15;
        int p = (row * 3277) >> 16;
#pragma unroll
        for (int kc = 0; kc < 2; ++kc) {
            int phys = (((kc * 4 + q) ^ (row & 7)) << 4);
            bf16x8 ub = *(const bf16x8*)(tile + row * 128 + phys);
            bf16x8 vb = *(const bf16x8*)(vt + p * 128 + kc * 64 + q * 16);
            bf16x8 o;
#pragma unroll
            for (int j = 0; j < 8; ++j) {
                float hval = bf2f((unsigned short)ub[j]) + bf2f((unsigned short)vb[j]);
                float t = fmaf(hval, r1[kc][j], mr1[kc][j]);
                t = fmaxf(t, SLOPE * t);
                o[j] = (short)f2bf(t);
            }
            bf[nt][kc] = o;
        }
    }
    __syncthreads();   // all waves done reading tile; now reuse it for h2
    // MFMA: C[m=cout][n=row]; lane holds row l15, couts mt*16+q*4..+3 -> packed b64 LDS write
#pragma unroll
    for (int nt = 0; nt < 5; ++nt) {
        int row = (w * 5 + nt) * 16 + l15;
        int r7 = row & 7;
#pragma unroll
        for (int mt = 0; mt < 4; ++mt) {
            f32x4 acc = (f32x4){0.f, 0.f, 0.f, 0.f};
            acc = __builtin_amdgcn_mfma_f32_16x16x32_bf16(aw[mt][0], bf[nt][0], acc, 0, 0, 0);
            acc = __builtin_amdgcn_mfma_f32_16x16x32_bf16(aw[mt][1], bf[nt][1], acc, 0, 0, 0);
            unsigned long long pk =
                (unsigned long long)((unsigned)f2bf(acc[0]) | ((unsigned)f2bf(acc[1]) << 16)) |
                ((unsigned long long)((unsigned)f2bf(acc[2]) | ((unsigned)f2bf(acc[3]) << 16)) << 32);
            int chunk = mt * 2 + (q >> 1);
            int addr = row * 128 + (((chunk ^ r7)) << 4) + (q & 1) * 8;
            *(unsigned long long*)(tile + addr) = pk;
        }
    }
    __syncthreads();
    // bulk store tile -> global (phys-linear; K3 re-stages identically)
    unsigned char* dstt = (unsigned char*)(h2g + (size_t)blockIdx.x * (320 * 64));
#pragma unroll
    for (int j2 = 0; j2 < 10; ++j2) {
        int off = j2 * 4096 + tid * 16;
        *(u32x4*)(dstt + off) = *(const u32x4*)(tile + off);
    }
    // stats2 from the completed tile
    {
        int c = tid & 63, g = tid >> 6;
        int chunkc = c >> 3, inb = (c & 7) * 2;
        float ss = 0.f, qs = 0.f;
        for (int jj = 0; jj < 80; ++jj) {
            int row = g * 80 + jj;
            float f = bf2f(*(const unsigned short*)(tile + row * 128 +
                         ((chunkc ^ (row & 7)) << 4) + inb));
            ss += f; qs += f * f;
        }
        red[tid] = ss; red[256 + tid] = qs;
    }
    __syncthreads();
    if (tid < 64) {
        float a = 0.f, b2 = 0.f;
        for (int g2 = 0; g2 < 4; ++g2) {
            a  += red[g2 * 64 + tid];
            b2 += red[256 + g2 * 64 + tid];
        }
        atomicAdd(&s2[b * 64 + tid], a);
        atomicAdd(&s2[512 + b * 64 + tid], b2);
    }
}

// ------ K3: stage h2 tile -> norm2+lrelu -> GEMM3 (A=W3) -> h3 tile -> max/stats3/out ------
__global__ __launch_bounds__(256) void k3_gemm3(const unsigned short* __restrict__ h2g,
        const float* __restrict__ W3, const float* __restrict__ s2,
        float* __restrict__ s3, float* __restrict__ out) {
    __shared__ __align__(16) unsigned char tile[40960];
    __shared__ float red[512];
    int tid = threadIdx.x;
    int lane = tid & 63, w = tid >> 6;
    int l15 = lane & 15, q = lane >> 4;
    int b = blockIdx.x >> 8;
    int n0 = (blockIdx.x & 255) << 4;
    int base = b * NPTS + n0;
    bf16x8 aw[4][2];
    load_bfrags(W3, l15, q, aw);
    const float inv = 1.0f / (float)NKCNT;
    float r2[2][8], mr2[2][8];
#pragma unroll
    for (int kc = 0; kc < 2; ++kc)
#pragma unroll
        for (int j = 0; j < 8; ++j) {
            int c = kc * 32 + q * 8 + j;
            float mm = s2[b * 64 + c] * inv;
            float vv = s2[512 + b * 64 + c] * inv - mm * mm;
            float rs = rsqrtf(vv + EPSI);
            r2[kc][j] = rs; mr2[kc][j] = -mm * rs;
        }
    const unsigned char* srct = (const unsigned char*)(h2g + (size_t)blockIdx.x * (320 * 64));
#pragma unroll
    for (int j = 0; j < 10; ++j) {
        int k = w * 10 + j;
        async16(srct + k * 1024 + lane * 16, tile + k * 1024);
    }
    __syncthreads();
    bf16x8 bf[5][2];
#pragma unroll
    for (int nt = 0; nt < 5; ++nt) {
        int row = (w * 5 + nt) * 16 + l15;
#pragma unroll
        for (int kc = 0; kc < 2; ++kc) {
            int phys = (((kc * 4 + q) ^ (row & 7)) << 4);
            bf16x8 hb = *(const bf16x8*)(tile + row * 128 + phys);
            bf16x8 o;
#pragma unroll
            for (int j = 0; j < 8; ++j) {
                float t = fmaf(bf2f((unsigned short)hb[j]), r2[kc][j], mr2[kc][j]);
                t = fmaxf(t, SLOPE * t);
                o[j] = (short)f2bf(t);
            }
            bf[nt][kc] = o;
        }
    }
    __syncthreads();
#pragma unroll
    for (int nt = 0; nt < 5; ++nt) {
        int row = (w * 5 + nt) * 16 + l15;
        int r7 = row & 7;
#pragma unroll
        for (int mt = 0; mt < 4; ++mt) {
            f32x4 acc = (f32x4){0.f, 0.f, 0.f, 0.f};
            acc = __builtin_amdgcn_mfma_f32_16x16x32_bf16(aw[mt][0], bf[nt][0], acc, 0, 0, 0);
            acc = __builtin_amdgcn_mfma_f32_16x16x32_bf16(aw[mt][1], bf[nt][1], acc, 0, 0, 0);
            unsigned long long pk =
                (unsigned long long)((unsigned)f2bf(acc[0]) | ((unsigned)f2bf(acc[1]) << 16)) |
                ((unsigned long long)((unsigned)f2bf(acc[2]) | ((unsigned)f2bf(acc[3]) << 16)) << 32);
            int chunk = mt * 2 + (q >> 1);
            int addr = row * 128 + (((chunk ^ r7)) << 4) + (q & 1) * 8;
            *(unsigned long long*)(tile + addr) = pk;
        }
    }
    __syncthreads();
    // pre-norm max over k=20 + stats3, from the completed h3 tile
    {
        int c = tid & 63, p0 = tid >> 6;
        int chunkc = c >> 3, inb = (c & 7) * 2;
        float ss = 0.f, qs = 0.f;
#pragma unroll
        for (int ii = 0; ii < 4; ++ii) {
            int p = p0 * 4 + ii;
            float mx = -3.4e38f;
            for (int kk = 0; kk < 20; ++kk) {
                int row = p * 20 + kk;
                float f = bf2f(*(const unsigned short*)(tile + row * 128 +
                             ((chunkc ^ (row & 7)) << 4) + inb));
                mx = fmaxf(mx, f);
                ss += f; qs += f * f;
            }
            out[(size_t)(base + p) * 64 + c] = mx;
        }
        red[tid] = ss; red[256 + tid] = qs;
    }
    __syncthreads();
    if (tid < 64) {
        float a = 0.f, b2 = 0.f;
        for (int g2 = 0; g2 < 4; ++g2) {
            a  += red[g2 * 64 + tid];
            b2 += red[256 + g2 * 64 + tid];
        }
        atomicAdd(&s3[b * 64 + tid], a);
        atomicAdd(&s3[512 + b * 64 + tid], b2);
    }
}

// ---------------- K4: out = lrelu((out - mean3) * rstd3), in place ----------------
__global__ __launch_bounds__(256) void k4_final(float* __restrict__ out,
        const float* __restrict__ s3) {
    int idx = blockIdx.x * 256 + threadIdx.x;
    int c = idx & 63;
    int b = idx >> 18;
    const float inv = 1.0f / (float)NKCNT;
    float mm = s3[b * 64 + c] * inv;
    float vv = s3[512 + b * 64 + c] * inv - mm * mm;
    float r = rsqrtf(vv + EPSI);
    float val = (out[idx] - mm) * r;
    out[idx] = val >= 0.f ? val : SLOPE * val;
}

extern "C" void kernel_launch(void* const* d_in, const int* in_sizes, int n_in,
                              void* d_out, int out_size, void* d_ws, size_t ws_size,
                              hipStream_t stream) {
    const float* x   = (const float*)d_in[0];
    const int*   ind = (const int*)d_in[1];
    const float* W1  = (const float*)d_in[2];
    const float* W2  = (const float*)d_in[3];
    const float* W3  = (const float*)d_in[4];
    float* out = (float*)d_out;

    unsigned short* u = (unsigned short*)d_ws;            // [32768][64] bf16
    unsigned short* v = u + BN * 64;                      // [32768][64] bf16
    float* stats = (float*)(v + BN * 64);
    float* s1 = stats;          // [2][512]
    float* s2 = stats + 1024;   // [2][512]
    float* s3 = stats + 2048;   // [2][512]
    unsigned short* h2 = (unsigned short*)(stats + 3 * 1024);  // [2048 tiles][320*64] bf16

    hipMemsetAsync(stats, 0, 3 * 1024 * sizeof(float), stream);
    k0_uv<<<dim3(BN / 16), dim3(256), 0, stream>>>(x, W1, u, v);
    k1_stats1<<<dim3(BN / 16), dim3(256), 0, stream>>>(u, v, ind, s1);
    k2_gemm2<<<dim3(BN / 16), dim3(256), 0, stream>>>(u, v, ind, W2, s1, s2, h2);
    k3_gemm3<<<dim3(BN / 16), dim3(256), 0, stream>>>(h2, W3, s2, s3, out);
    k4_final<<<dim3(BN * 64 / 256), dim3(256), 0, stream>>>(out, s3);
}